// Round 5
// baseline (363.084 us; speedup 1.0000x reference)
//
#include <hip/hip_runtime.h>
#include <hip/hip_bf16.h>

#define NEG_SLOPE 0.2f
#define LN_EPS 1e-5f
#define SM_EPS 1e-16f

typedef __attribute__((ext_vector_type(8))) short bf16x8;
typedef __attribute__((ext_vector_type(4))) float f32x4;

__device__ inline unsigned short f2bf(float f) {
    unsigned u = __float_as_uint(f);
    return (unsigned short)((u + 0x7FFFu + ((u >> 16) & 1u)) >> 16);
}
__device__ inline float bf_lo(unsigned int v) { return __uint_as_float(v << 16); }
__device__ inline float bf_hi(unsigned int v) { return __uint_as_float(v & 0xffff0000u); }

// ---------------------------------------------------------------------------
// k_wconv: one-time W (f32 [128x128]) -> bf16 row-major Wb. L1/L2-resident.
// ---------------------------------------------------------------------------
__global__ __launch_bounds__(256) void k_wconv(const float* __restrict__ W,
                                               unsigned short* __restrict__ Wb) {
    int i = blockIdx.x * 256 + threadIdx.x;      // float4 index, 4096 total
    float4 v = reinterpret_cast<const float4*>(W)[i];
    ushort4 b;
    b.x = f2bf(v.x); b.y = f2bf(v.y); b.z = f2bf(v.z); b.w = f2bf(v.w);
    reinterpret_cast<ushort4*>(Wb)[i] = b;
}

// ---------------------------------------------------------------------------
// K1: bf16-MFMA GEMM + attention dots + bf16 pack.
// LDS holds only the X tile (17 KB) -> 8 blocks/CU. B-fragments load directly
// from global Wb (32 KB, L1-hot). Wave w: rows w*16..+15, 8 col-tiles of 16.
// ---------------------------------------------------------------------------
__global__ __launch_bounds__(256) void k_gemm(const float* __restrict__ X,
                                              const unsigned short* __restrict__ Wb,
                                              const float* __restrict__ att_src,
                                              const float* __restrict__ att_dst,
                                              unsigned int* __restrict__ xp,
                                              float2* __restrict__ aS,
                                              float2* __restrict__ aD, int N) {
    __shared__ unsigned short Xs[64 * 136];
    const int t = threadIdx.x;
    const int b0 = blockIdx.x * 64;
    const int lane = t & 63;
    const int w = t >> 6;
    const int c15 = lane & 15;
    const int quad = lane >> 4;

#pragma unroll
    for (int i = 0; i < 8; ++i) {
        int f = i * 256 + t;
        int m = f >> 5;
        int q = f & 31;
        int gr = b0 + m;
        if (gr >= N) gr = N - 1;
        float4 v = reinterpret_cast<const float4*>(X)[(size_t)gr * 32 + q];
        ushort4 b;
        b.x = f2bf(v.x); b.y = f2bf(v.y); b.z = f2bf(v.z); b.w = f2bf(v.w);
        *reinterpret_cast<ushort4*>(&Xs[m * 136 + q * 4]) = b;
    }
    __syncthreads();

    f32x4 acc[8];
#pragma unroll
    for (int ct = 0; ct < 8; ++ct) acc[ct] = (f32x4){0.f, 0.f, 0.f, 0.f};

#pragma unroll
    for (int kc = 0; kc < 4; ++kc) {
        bf16x8 af = *reinterpret_cast<const bf16x8*>(
            &Xs[(w * 16 + c15) * 136 + kc * 32 + quad * 8]);
#pragma unroll
        for (int ct = 0; ct < 8; ++ct) {
            bf16x8 bfr = *reinterpret_cast<const bf16x8*>(
                &Wb[(ct * 16 + c15) * 128 + kc * 32 + quad * 8]);
            acc[ct] = __builtin_amdgcn_mfma_f32_16x16x32_bf16(af, bfr, acc[ct], 0, 0, 0);
        }
    }

    float attS[8], attD[8];
#pragma unroll
    for (int ct = 0; ct < 8; ++ct) {
        attS[ct] = att_src[ct * 16 + c15];
        attD[ct] = att_dst[ct * 16 + c15];
    }

#pragma unroll
    for (int r = 0; r < 4; ++r) {
        int row = b0 + w * 16 + quad * 4 + r;
        float s0 = 0.f, s1 = 0.f, d0 = 0.f, d1 = 0.f;
#pragma unroll
        for (int ct = 0; ct < 4; ++ct) {
            s0 += acc[ct][r] * attS[ct];
            d0 += acc[ct][r] * attD[ct];
            s1 += acc[ct + 4][r] * attS[ct + 4];
            d1 += acc[ct + 4][r] * attD[ct + 4];
        }
#pragma unroll
        for (int o = 1; o < 16; o <<= 1) {
            s0 += __shfl_xor(s0, o);
            s1 += __shfl_xor(s1, o);
            d0 += __shfl_xor(d0, o);
            d1 += __shfl_xor(d1, o);
        }
        if (row < N) {
#pragma unroll
            for (int ct = 0; ct < 4; ++ct) {
                unsigned int p = (unsigned int)f2bf(acc[ct][r]) |
                                 ((unsigned int)f2bf(acc[ct + 4][r]) << 16);
                xp[(size_t)row * 64 + ct * 16 + c15] = p;
            }
            if (c15 == 0) {
                aS[row] = make_float2(s0, s1);
                aD[row] = make_float2(d0, d1);
            }
        }
    }
}

// ---------------------------------------------------------------------------
// Atomic-free CSR build via 2-level counting sort on dst.
// ---------------------------------------------------------------------------
#define SORT_CHUNK 8192
#define NBIN 512

__global__ __launch_bounds__(256) void k_sort_count(const int* __restrict__ ei,
                                                    int* __restrict__ blockCnt,
                                                    int E, int NB) {
    __shared__ int hist[NBIN];
    const int t = threadIdx.x;
    for (int i = t; i < NBIN; i += 256) hist[i] = 0;
    __syncthreads();
    const int base = blockIdx.x * SORT_CHUNK;
#pragma unroll
    for (int k = 0; k < 32; ++k) {
        int i = base + k * 256 + t;
        if (i < E) atomicAdd(&hist[ei[E + i] >> 8], 1);
    }
    __syncthreads();
    for (int i = t; i < NBIN; i += 256)
        blockCnt[i * NB + blockIdx.x] = hist[i];
}

__global__ __launch_bounds__(256) void k_scan1(const int* __restrict__ data,
                                               int* __restrict__ blockSums, int M) {
    __shared__ int lds[4];
    const int t = threadIdx.x;
    int base = blockIdx.x * 1024 + t * 4;
    int s = 0;
    for (int c = 0; c < 4; ++c) {
        int i = base + c;
        if (i < M) s += data[i];
    }
    int lane = t & 63, w = t >> 6;
    for (int o = 32; o > 0; o >>= 1) s += __shfl_down(s, o);
    if (lane == 0) lds[w] = s;
    __syncthreads();
    if (t == 0) blockSums[blockIdx.x] = lds[0] + lds[1] + lds[2] + lds[3];
}

__global__ void k_scan2(int* __restrict__ blockSums, int nb) {
    __shared__ int buf[256];
    const int t = threadIdx.x;
    int v = (t < nb) ? blockSums[t] : 0;
    buf[t] = v;
    __syncthreads();
    for (int o = 1; o < 256; o <<= 1) {
        int u = (t >= o) ? buf[t - o] : 0;
        __syncthreads();
        buf[t] += u;
        __syncthreads();
    }
    if (t < nb) blockSums[t] = buf[t] - v;
}

__global__ __launch_bounds__(256) void k_scan3(int* __restrict__ data,
                                               const int* __restrict__ blockSums, int M) {
    __shared__ int lds[4];
    const int t = threadIdx.x;
    int base = blockIdx.x * 1024 + t * 4;
    int c[4];
    int s = 0;
#pragma unroll
    for (int i = 0; i < 4; ++i) {
        int idx = base + i;
        c[i] = (idx < M) ? data[idx] : 0;
        s += c[i];
    }
    int lane = t & 63, w = t >> 6;
    int incl = s;
#pragma unroll
    for (int o = 1; o < 64; o <<= 1) {
        int u = __shfl_up(incl, o);
        if (lane >= o) incl += u;
    }
    if (lane == 63) lds[w] = incl;
    __syncthreads();
    if (t == 0) {
        int run = 0;
        for (int i = 0; i < 4; ++i) { int tmp = lds[i]; lds[i] = run; run += tmp; }
    }
    __syncthreads();
    int off = blockSums[blockIdx.x] + lds[w] + incl - s;
#pragma unroll
    for (int i = 0; i < 4; ++i) {
        int idx = base + i;
        if (idx < M) { data[idx] = off; off += c[i]; }
    }
}

// k_sort_scatter: computes exp weights ONCE (thread-per-edge; aS/aD are
// L2-resident) and scatters dst/src/packed-u into bucket-contiguous arrays.
__global__ __launch_bounds__(256) void k_sort_scatter(const int* __restrict__ ei,
                                                      const int* __restrict__ scanned,
                                                      const float2* __restrict__ aS,
                                                      const float2* __restrict__ aD,
                                                      unsigned int* __restrict__ tmpDst,
                                                      unsigned int* __restrict__ tmpSrc,
                                                      unsigned int* __restrict__ tmpU,
                                                      int E, int NB) {
    __shared__ int off[NBIN];
    const int t = threadIdx.x;
    for (int i = t; i < NBIN; i += 256) off[i] = scanned[i * NB + blockIdx.x];
    __syncthreads();
    const int base = blockIdx.x * SORT_CHUNK;
#pragma unroll
    for (int k = 0; k < 32; ++k) {
        int i = base + k * 256 + t;
        if (i < E) {
            int s = ei[i];
            int d = ei[E + i];
            float2 a = aS[s];
            float2 ad2 = aD[d];
            float f0 = a.x + ad2.x; f0 = fmaxf(f0, NEG_SLOPE * f0);
            float f1 = a.y + ad2.y; f1 = fmaxf(f1, NEG_SLOPE * f1);
            unsigned int pk = (unsigned int)f2bf(__expf(f0)) |
                              ((unsigned int)f2bf(__expf(f1)) << 16);
            int p = atomicAdd(&off[d >> 8], 1);
            tmpDst[p] = (unsigned)d;
            tmpSrc[p] = (unsigned)s;
            tmpU[p] = pk;
        }
    }
}

// ---------------------------------------------------------------------------
// k_bucket: one block per 256-dst bucket. P1: coalesced denominator/count
// accumulation from pre-computed weights. Then row_ptr + self-loop + inv
// (0.5 head-mean folded in). P2: coalesced re-read, emit CSR uint2
// {src, bf16(alpha0)|bf16(alpha1)<<16} with alpha pre-normalized & halved.
// ---------------------------------------------------------------------------
__global__ __launch_bounds__(256) void k_bucket(const unsigned int* __restrict__ tmpDst,
                                                const unsigned int* __restrict__ tmpSrc,
                                                const unsigned int* __restrict__ tmpU,
                                                const int* __restrict__ scanned,
                                                const float2* __restrict__ aS,
                                                const float2* __restrict__ aD,
                                                uint2* __restrict__ csr,
                                                int* __restrict__ row_ptr,
                                                float2* __restrict__ alphaSelf,
                                                int E, int NB, int N) {
    __shared__ int cnt[256];
    __shared__ int cur[256];
    __shared__ float den0[256], den1[256];
    __shared__ float inv0[256], inv1[256];
    __shared__ int lds[4];
    const int t = threadIdx.x;
    const int b = blockIdx.x;
    const int start = scanned[b * NB];
    const int end = (b + 1 < NBIN) ? scanned[(b + 1) * NB] : E;
    const int m = end - start;

    cnt[t] = 0; den0[t] = 0.f; den1[t] = 0.f;
    __syncthreads();

    for (int k = t; k < m; k += 256) {
        unsigned int d = tmpDst[start + k];
        unsigned int pk = tmpU[start + k];
        int li = d & 255;
        atomicAdd(&cnt[li], 1);
        atomicAdd(&den0[li], bf_lo(pk));
        atomicAdd(&den1[li], bf_hi(pk));
    }
    __syncthreads();

    int v = cnt[t];
    int lane = t & 63, w = t >> 6;
    int incl = v;
#pragma unroll
    for (int o = 1; o < 64; o <<= 1) {
        int u = __shfl_up(incl, o);
        if (lane >= o) incl += u;
    }
    if (lane == 63) lds[w] = incl;
    __syncthreads();
    if (t == 0) {
        int run = 0;
        for (int i = 0; i < 4; ++i) { int tmpv = lds[i]; lds[i] = run; run += tmpv; }
    }
    __syncthreads();
    int excl = lds[w] + incl - v;
    cur[t] = start + excl;

    int d = b * 256 + t;
    float iv0 = 0.f, iv1 = 0.f;
    if (d < N) {
        float2 a = aS[d];
        float2 ad2 = aD[d];
        float f0 = a.x + ad2.x; f0 = fmaxf(f0, NEG_SLOPE * f0);
        float f1 = a.y + ad2.y; f1 = fmaxf(f1, NEG_SLOPE * f1);
        float ws0 = __expf(f0), ws1 = __expf(f1);
        float D0 = den0[t] + ws0, D1 = den1[t] + ws1;
        iv0 = 0.5f / (D0 + SM_EPS);            // 0.5 = head-mean fold
        iv1 = 0.5f / (D1 + SM_EPS);
        alphaSelf[d] = make_float2(ws0 * iv0, ws1 * iv1);
        row_ptr[d] = start + excl;
    }
    inv0[t] = iv0; inv1[t] = iv1;
    if (b == 0 && t == 0) row_ptr[N] = E;
    __syncthreads();

    for (int k = t; k < m; k += 256) {
        unsigned int dd = tmpDst[start + k];
        unsigned int ss = tmpSrc[start + k];
        unsigned int pk = tmpU[start + k];
        int li = dd & 255;
        float a0 = bf_lo(pk) * inv0[li];
        float a1 = bf_hi(pk) * inv1[li];
        int p = atomicAdd(&cur[li], 1);
        csr[p] = make_uint2(ss, (unsigned int)f2bf(a0) |
                                ((unsigned int)f2bf(a1) << 16));
    }
}

// ---------------------------------------------------------------------------
// K5: per-dst aggregation + bias + LayerNorm. Head-mean folded into alpha:
// per edge per lane: 8B broadcast CSR + 256B gather + 2 FMA (fused S).
// ---------------------------------------------------------------------------
__global__ __launch_bounds__(256) void k_agg(const unsigned int* __restrict__ xp,
                                             const float2* __restrict__ alphaSelf,
                                             const int* __restrict__ row_ptr,
                                             const uint2* __restrict__ csr,
                                             const float* __restrict__ bias,
                                             const float* __restrict__ gamma,
                                             const float* __restrict__ beta,
                                             float* __restrict__ out, int N) {
    const int w = threadIdx.x >> 6, lane = threadIdx.x & 63;
    const int n = blockIdx.x * 4 + w;
    if (n >= N) return;

    float2 asf = alphaSelf[n];
    unsigned int vself = xp[(size_t)n * 64 + lane];
    float S = asf.x * bf_lo(vself) + asf.y * bf_hi(vself);

    const int jb = row_ptr[n], je = row_ptr[n + 1];
    int j = jb;
    for (; j + 3 < je; j += 4) {
        uint2 c0 = csr[j], c1 = csr[j + 1], c2 = csr[j + 2], c3 = csr[j + 3];
        unsigned int v0 = xp[(size_t)c0.x * 64 + lane];
        unsigned int v1 = xp[(size_t)c1.x * 64 + lane];
        unsigned int v2 = xp[(size_t)c2.x * 64 + lane];
        unsigned int v3 = xp[(size_t)c3.x * 64 + lane];
        S += bf_lo(c0.y) * bf_lo(v0) + bf_hi(c0.y) * bf_hi(v0);
        S += bf_lo(c1.y) * bf_lo(v1) + bf_hi(c1.y) * bf_hi(v1);
        S += bf_lo(c2.y) * bf_lo(v2) + bf_hi(c2.y) * bf_hi(v2);
        S += bf_lo(c3.y) * bf_lo(v3) + bf_hi(c3.y) * bf_hi(v3);
    }
    for (; j < je; ++j) {
        uint2 c = csr[j];
        unsigned int vv = xp[(size_t)c.x * 64 + lane];
        S += bf_lo(c.y) * bf_lo(vv) + bf_hi(c.y) * bf_hi(vv);
    }

    float o = S + bias[lane];

    float mu = o;
#pragma unroll
    for (int d = 32; d > 0; d >>= 1) mu += __shfl_xor(mu, d);
    mu *= (1.0f / 64.0f);
    float dv = o - mu;
    float var = dv * dv;
#pragma unroll
    for (int d = 32; d > 0; d >>= 1) var += __shfl_xor(var, d);
    var *= (1.0f / 64.0f);
    out[(size_t)n * 64 + lane] = dv * rsqrtf(var + LN_EPS) * gamma[lane] + beta[lane];
}

// ---------------------------------------------------------------------------
extern "C" void kernel_launch(void* const* d_in, const int* in_sizes, int n_in,
                              void* d_out, int out_size, void* d_ws, size_t ws_size,
                              hipStream_t stream) {
    const float* X        = (const float*)d_in[0];
    const int*   ei       = (const int*)d_in[1];
    const float* W        = (const float*)d_in[2];
    const float* att_src  = (const float*)d_in[3];
    const float* att_dst  = (const float*)d_in[4];
    const float* bias     = (const float*)d_in[5];
    const float* ln_gamma = (const float*)d_in[6];
    const float* ln_beta  = (const float*)d_in[7];
    float* out = (float*)d_out;

    const int N = in_sizes[0] / 128;
    const int E = in_sizes[1] / 2;
    const int NB = (E + SORT_CHUNK - 1) / SORT_CHUNK;
    const int NBUCK = (N + 255) / 256;
    const int M = NBIN * NB;

    char* ws = (char*)d_ws;
    size_t off = 0;
    auto alloc = [&](size_t bytes) {
        size_t o = off;
        off += (bytes + 255) & ~(size_t)255;
        return o;
    };
    unsigned int* xp     = (unsigned int*)(ws + alloc((size_t)N * 64 * 4));
    float2* aS           = (float2*)(ws + alloc((size_t)N * 8));
    float2* aD           = (float2*)(ws + alloc((size_t)N * 8));
    float2* alphaSelf    = (float2*)(ws + alloc((size_t)N * 8));
    int* row_ptr         = (int*)(ws + alloc((size_t)(N + 1) * 4));
    uint2* csr           = (uint2*)(ws + alloc((size_t)E * 8));
    unsigned int* tmpDst = (unsigned int*)(ws + alloc((size_t)E * 4));
    unsigned int* tmpSrc = (unsigned int*)(ws + alloc((size_t)E * 4));
    unsigned int* tmpU   = (unsigned int*)(ws + alloc((size_t)E * 4));
    int* blockCnt        = (int*)(ws + alloc((size_t)M * 4));
    int* blockSums       = (int*)(ws + alloc(256 * 4));
    unsigned short* Wb   = (unsigned short*)(ws + alloc(128 * 128 * 2));

    k_wconv<<<16, 256, 0, stream>>>(W, Wb);
    k_gemm<<<(N + 63) / 64, 256, 0, stream>>>(X, Wb, att_src, att_dst, xp, aS, aD, N);

    k_sort_count<<<NB, 256, 0, stream>>>(ei, blockCnt, E, NB);
    const int nb = (M + 1023) / 1024;
    k_scan1<<<nb, 256, 0, stream>>>(blockCnt, blockSums, M);
    k_scan2<<<1, 256, 0, stream>>>(blockSums, nb);
    k_scan3<<<nb, 256, 0, stream>>>(blockCnt, blockSums, M);
    k_sort_scatter<<<NB, 256, 0, stream>>>(ei, blockCnt, aS, aD,
                                           tmpDst, tmpSrc, tmpU, E, NB);
    k_bucket<<<NBUCK, 256, 0, stream>>>(tmpDst, tmpSrc, tmpU, blockCnt, aS, aD,
                                        csr, row_ptr, alphaSelf, E, NB, N);

    k_agg<<<(N + 3) / 4, 256, 0, stream>>>(xp, alphaSelf, row_ptr, csr,
                                           bias, ln_gamma, ln_beta, out, N);
}

// Round 6
// 296.520 us; speedup vs baseline: 1.2245x; 1.2245x over previous
//
#include <hip/hip_runtime.h>
#include <hip/hip_bf16.h>

#define NEG_SLOPE 0.2f
#define LN_EPS 1e-5f
#define SM_EPS 1e-16f

typedef __attribute__((ext_vector_type(8))) short bf16x8;
typedef __attribute__((ext_vector_type(4))) float f32x4;

__device__ inline unsigned short f2bf(float f) {
    unsigned u = __float_as_uint(f);
    return (unsigned short)((u + 0x7FFFu + ((u >> 16) & 1u)) >> 16);
}
__device__ inline float bf_lo(unsigned int v) { return __uint_as_float(v << 16); }
__device__ inline float bf_hi(unsigned int v) { return __uint_as_float(v & 0xffff0000u); }

// ---------------------------------------------------------------------------
// k_wconv: one-time W (f32 [128x128]) -> bf16 row-major Wb.
// ---------------------------------------------------------------------------
__global__ __launch_bounds__(256) void k_wconv(const float* __restrict__ W,
                                               unsigned short* __restrict__ Wb) {
    int i = blockIdx.x * 256 + threadIdx.x;
    float4 v = reinterpret_cast<const float4*>(W)[i];
    ushort4 b;
    b.x = f2bf(v.x); b.y = f2bf(v.y); b.z = f2bf(v.z); b.w = f2bf(v.w);
    reinterpret_cast<ushort4*>(Wb)[i] = b;
}

// ---------------------------------------------------------------------------
// K1: bf16-MFMA GEMM + attention dots + bf16 pack. (round-5 version, 17KB LDS)
// ---------------------------------------------------------------------------
__global__ __launch_bounds__(256) void k_gemm(const float* __restrict__ X,
                                              const unsigned short* __restrict__ Wb,
                                              const float* __restrict__ att_src,
                                              const float* __restrict__ att_dst,
                                              unsigned int* __restrict__ xp,
                                              float2* __restrict__ aS,
                                              float2* __restrict__ aD, int N) {
    __shared__ unsigned short Xs[64 * 136];
    const int t = threadIdx.x;
    const int b0 = blockIdx.x * 64;
    const int lane = t & 63;
    const int w = t >> 6;
    const int c15 = lane & 15;
    const int quad = lane >> 4;

#pragma unroll
    for (int i = 0; i < 8; ++i) {
        int f = i * 256 + t;
        int m = f >> 5;
        int q = f & 31;
        int gr = b0 + m;
        if (gr >= N) gr = N - 1;
        float4 v = reinterpret_cast<const float4*>(X)[(size_t)gr * 32 + q];
        ushort4 b;
        b.x = f2bf(v.x); b.y = f2bf(v.y); b.z = f2bf(v.z); b.w = f2bf(v.w);
        *reinterpret_cast<ushort4*>(&Xs[m * 136 + q * 4]) = b;
    }
    __syncthreads();

    f32x4 acc[8];
#pragma unroll
    for (int ct = 0; ct < 8; ++ct) acc[ct] = (f32x4){0.f, 0.f, 0.f, 0.f};

#pragma unroll
    for (int kc = 0; kc < 4; ++kc) {
        bf16x8 af = *reinterpret_cast<const bf16x8*>(
            &Xs[(w * 16 + c15) * 136 + kc * 32 + quad * 8]);
#pragma unroll
        for (int ct = 0; ct < 8; ++ct) {
            bf16x8 bfr = *reinterpret_cast<const bf16x8*>(
                &Wb[(ct * 16 + c15) * 128 + kc * 32 + quad * 8]);
            acc[ct] = __builtin_amdgcn_mfma_f32_16x16x32_bf16(af, bfr, acc[ct], 0, 0, 0);
        }
    }

    float attS[8], attD[8];
#pragma unroll
    for (int ct = 0; ct < 8; ++ct) {
        attS[ct] = att_src[ct * 16 + c15];
        attD[ct] = att_dst[ct * 16 + c15];
    }

#pragma unroll
    for (int r = 0; r < 4; ++r) {
        int row = b0 + w * 16 + quad * 4 + r;
        float s0 = 0.f, s1 = 0.f, d0 = 0.f, d1 = 0.f;
#pragma unroll
        for (int ct = 0; ct < 4; ++ct) {
            s0 += acc[ct][r] * attS[ct];
            d0 += acc[ct][r] * attD[ct];
            s1 += acc[ct + 4][r] * attS[ct + 4];
            d1 += acc[ct + 4][r] * attD[ct + 4];
        }
#pragma unroll
        for (int o = 1; o < 16; o <<= 1) {
            s0 += __shfl_xor(s0, o);
            s1 += __shfl_xor(s1, o);
            d0 += __shfl_xor(d0, o);
            d1 += __shfl_xor(d1, o);
        }
        if (row < N) {
#pragma unroll
            for (int ct = 0; ct < 4; ++ct) {
                unsigned int p = (unsigned int)f2bf(acc[ct][r]) |
                                 ((unsigned int)f2bf(acc[ct + 4][r]) << 16);
                xp[(size_t)row * 64 + ct * 16 + c15] = p;
            }
            if (c15 == 0) {
                aS[row] = make_float2(s0, s1);
                aD[row] = make_float2(d0, d1);
            }
        }
    }
}

// ---------------------------------------------------------------------------
// k_uw: one thread per edge, full grid. exp weights computed ONCE, written
// coalesced. aS/aD tables (800KB each) are L2-resident -> gathers are L2 hits.
// ---------------------------------------------------------------------------
__global__ __launch_bounds__(256) void k_uw(const int* __restrict__ ei,
                                            const float2* __restrict__ aS,
                                            const float2* __restrict__ aD,
                                            unsigned int* __restrict__ uW, int E) {
    int i = blockIdx.x * 256 + threadIdx.x;
    if (i >= E) return;
    int s = ei[i];
    int d = ei[E + i];
    float2 a = aS[s];
    float2 ad2 = aD[d];
    float f0 = a.x + ad2.x; f0 = fmaxf(f0, NEG_SLOPE * f0);
    float f1 = a.y + ad2.y; f1 = fmaxf(f1, NEG_SLOPE * f1);
    uW[i] = (unsigned int)f2bf(__expf(f0)) |
            ((unsigned int)f2bf(__expf(f1)) << 16);
}

// ---------------------------------------------------------------------------
// Atomic-free CSR build via 2-level counting sort on dst. CHUNK=4096 (391 blk).
// ---------------------------------------------------------------------------
#define SORT_CHUNK 4096
#define NBIN 512

__global__ __launch_bounds__(256) void k_sort_count(const int* __restrict__ ei,
                                                    int* __restrict__ blockCnt,
                                                    int E, int NB) {
    __shared__ int hist[NBIN];
    const int t = threadIdx.x;
    for (int i = t; i < NBIN; i += 256) hist[i] = 0;
    __syncthreads();
    const int base = blockIdx.x * SORT_CHUNK;
#pragma unroll
    for (int k = 0; k < 16; ++k) {
        int i = base + k * 256 + t;
        if (i < E) atomicAdd(&hist[ei[E + i] >> 8], 1);
    }
    __syncthreads();
    for (int i = t; i < NBIN; i += 256)
        blockCnt[i * NB + blockIdx.x] = hist[i];
}

__global__ __launch_bounds__(256) void k_scan1(const int* __restrict__ data,
                                               int* __restrict__ blockSums, int M) {
    __shared__ int lds[4];
    const int t = threadIdx.x;
    int base = blockIdx.x * 1024 + t * 4;
    int s = 0;
    for (int c = 0; c < 4; ++c) {
        int i = base + c;
        if (i < M) s += data[i];
    }
    int lane = t & 63, w = t >> 6;
    for (int o = 32; o > 0; o >>= 1) s += __shfl_down(s, o);
    if (lane == 0) lds[w] = s;
    __syncthreads();
    if (t == 0) blockSums[blockIdx.x] = lds[0] + lds[1] + lds[2] + lds[3];
}

__global__ void k_scan2(int* __restrict__ blockSums, int nb) {
    __shared__ int buf[256];
    const int t = threadIdx.x;
    int v = (t < nb) ? blockSums[t] : 0;
    buf[t] = v;
    __syncthreads();
    for (int o = 1; o < 256; o <<= 1) {
        int u = (t >= o) ? buf[t - o] : 0;
        __syncthreads();
        buf[t] += u;
        __syncthreads();
    }
    if (t < nb) blockSums[t] = buf[t] - v;
}

__global__ __launch_bounds__(256) void k_scan3(int* __restrict__ data,
                                               const int* __restrict__ blockSums, int M) {
    __shared__ int lds[4];
    const int t = threadIdx.x;
    int base = blockIdx.x * 1024 + t * 4;
    int c[4];
    int s = 0;
#pragma unroll
    for (int i = 0; i < 4; ++i) {
        int idx = base + i;
        c[i] = (idx < M) ? data[idx] : 0;
        s += c[i];
    }
    int lane = t & 63, w = t >> 6;
    int incl = s;
#pragma unroll
    for (int o = 1; o < 64; o <<= 1) {
        int u = __shfl_up(incl, o);
        if (lane >= o) incl += u;
    }
    if (lane == 63) lds[w] = incl;
    __syncthreads();
    if (t == 0) {
        int run = 0;
        for (int i = 0; i < 4; ++i) { int tmp = lds[i]; lds[i] = run; run += tmp; }
    }
    __syncthreads();
    int off = blockSums[blockIdx.x] + lds[w] + incl - s;
#pragma unroll
    for (int i = 0; i < 4; ++i) {
        int idx = base + i;
        if (idx < M) { data[idx] = off; off += c[i]; }
    }
}

// k_sort_scatter: lean — reads ei + precomputed uW (both coalesced), one uint2
// store per edge: {(dst&255)<<24 | src, uPacked}. src fits in 24 bits.
__global__ __launch_bounds__(256) void k_sort_scatter(const int* __restrict__ ei,
                                                      const unsigned int* __restrict__ uW,
                                                      const int* __restrict__ scanned,
                                                      uint2* __restrict__ tmp,
                                                      int E, int NB) {
    __shared__ int off[NBIN];
    const int t = threadIdx.x;
    for (int i = t; i < NBIN; i += 256) off[i] = scanned[i * NB + blockIdx.x];
    __syncthreads();
    const int base = blockIdx.x * SORT_CHUNK;
#pragma unroll
    for (int k = 0; k < 16; ++k) {
        int i = base + k * 256 + t;
        if (i < E) {
            int s = ei[i];
            int d = ei[E + i];
            unsigned int u = uW[i];
            int p = atomicAdd(&off[d >> 8], 1);
            tmp[p] = make_uint2(((unsigned)(d & 255) << 24) | (unsigned)s, u);
        }
    }
}

// ---------------------------------------------------------------------------
// k_bucket: one block per 256-dst bucket, pure coalesced two-pass.
// P1: denominators/counts from tmp. Then row_ptr + self-loop + 0.5/D.
// P2: emit CSR uint2 {src, bf16(alpha0)|bf16(alpha1)<<16}, alpha half-folded.
// ---------------------------------------------------------------------------
__global__ __launch_bounds__(256) void k_bucket(const uint2* __restrict__ tmp,
                                                const int* __restrict__ scanned,
                                                const float2* __restrict__ aS,
                                                const float2* __restrict__ aD,
                                                uint2* __restrict__ csr,
                                                int* __restrict__ row_ptr,
                                                float2* __restrict__ alphaSelf,
                                                int E, int NB, int N) {
    __shared__ int cnt[256];
    __shared__ int cur[256];
    __shared__ float den0[256], den1[256];
    __shared__ float inv0[256], inv1[256];
    __shared__ int lds[4];
    const int t = threadIdx.x;
    const int b = blockIdx.x;
    const int start = scanned[b * NB];
    const int end = (b + 1 < NBIN) ? scanned[(b + 1) * NB] : E;
    const int m = end - start;

    cnt[t] = 0; den0[t] = 0.f; den1[t] = 0.f;
    __syncthreads();

    for (int k = t; k < m; k += 256) {
        uint2 e = tmp[start + k];
        int li = e.x >> 24;
        atomicAdd(&cnt[li], 1);
        atomicAdd(&den0[li], bf_lo(e.y));
        atomicAdd(&den1[li], bf_hi(e.y));
    }
    __syncthreads();

    int v = cnt[t];
    int lane = t & 63, w = t >> 6;
    int incl = v;
#pragma unroll
    for (int o = 1; o < 64; o <<= 1) {
        int u = __shfl_up(incl, o);
        if (lane >= o) incl += u;
    }
    if (lane == 63) lds[w] = incl;
    __syncthreads();
    if (t == 0) {
        int run = 0;
        for (int i = 0; i < 4; ++i) { int tmpv = lds[i]; lds[i] = run; run += tmpv; }
    }
    __syncthreads();
    int excl = lds[w] + incl - v;
    cur[t] = start + excl;

    int d = b * 256 + t;
    float iv0 = 0.f, iv1 = 0.f;
    if (d < N) {
        float2 a = aS[d];
        float2 ad2 = aD[d];
        float f0 = a.x + ad2.x; f0 = fmaxf(f0, NEG_SLOPE * f0);
        float f1 = a.y + ad2.y; f1 = fmaxf(f1, NEG_SLOPE * f1);
        float ws0 = __expf(f0), ws1 = __expf(f1);
        float D0 = den0[t] + ws0, D1 = den1[t] + ws1;
        iv0 = 0.5f / (D0 + SM_EPS);            // 0.5 = head-mean fold
        iv1 = 0.5f / (D1 + SM_EPS);
        alphaSelf[d] = make_float2(ws0 * iv0, ws1 * iv1);
        row_ptr[d] = start + excl;
    }
    inv0[t] = iv0; inv1[t] = iv1;
    if (b == 0 && t == 0) row_ptr[N] = E;
    __syncthreads();

    for (int k = t; k < m; k += 256) {
        uint2 e = tmp[start + k];
        int li = e.x >> 24;
        float a0 = bf_lo(e.y) * inv0[li];
        float a1 = bf_hi(e.y) * inv1[li];
        int p = atomicAdd(&cur[li], 1);
        csr[p] = make_uint2(e.x & 0x00FFFFFFu,
                            (unsigned int)f2bf(a0) | ((unsigned int)f2bf(a1) << 16));
    }
}

// ---------------------------------------------------------------------------
// K5: per-dst aggregation + bias + LayerNorm. 8B CSR broadcast + 256B gather
// + 2 FMA per edge; head-mean pre-folded into alpha.
// ---------------------------------------------------------------------------
__global__ __launch_bounds__(256) void k_agg(const unsigned int* __restrict__ xp,
                                             const float2* __restrict__ alphaSelf,
                                             const int* __restrict__ row_ptr,
                                             const uint2* __restrict__ csr,
                                             const float* __restrict__ bias,
                                             const float* __restrict__ gamma,
                                             const float* __restrict__ beta,
                                             float* __restrict__ out, int N) {
    const int w = threadIdx.x >> 6, lane = threadIdx.x & 63;
    const int n = blockIdx.x * 4 + w;
    if (n >= N) return;

    float2 asf = alphaSelf[n];
    unsigned int vself = xp[(size_t)n * 64 + lane];
    float S = asf.x * bf_lo(vself) + asf.y * bf_hi(vself);

    const int jb = row_ptr[n], je = row_ptr[n + 1];
    int j = jb;
    for (; j + 3 < je; j += 4) {
        uint2 c0 = csr[j], c1 = csr[j + 1], c2 = csr[j + 2], c3 = csr[j + 3];
        unsigned int v0 = xp[(size_t)c0.x * 64 + lane];
        unsigned int v1 = xp[(size_t)c1.x * 64 + lane];
        unsigned int v2 = xp[(size_t)c2.x * 64 + lane];
        unsigned int v3 = xp[(size_t)c3.x * 64 + lane];
        S += bf_lo(c0.y) * bf_lo(v0) + bf_hi(c0.y) * bf_hi(v0);
        S += bf_lo(c1.y) * bf_lo(v1) + bf_hi(c1.y) * bf_hi(v1);
        S += bf_lo(c2.y) * bf_lo(v2) + bf_hi(c2.y) * bf_hi(v2);
        S += bf_lo(c3.y) * bf_lo(v3) + bf_hi(c3.y) * bf_hi(v3);
    }
    for (; j < je; ++j) {
        uint2 c = csr[j];
        unsigned int vv = xp[(size_t)c.x * 64 + lane];
        S += bf_lo(c.y) * bf_lo(vv) + bf_hi(c.y) * bf_hi(vv);
    }

    float o = S + bias[lane];

    float mu = o;
#pragma unroll
    for (int d = 32; d > 0; d >>= 1) mu += __shfl_xor(mu, d);
    mu *= (1.0f / 64.0f);
    float dv = o - mu;
    float var = dv * dv;
#pragma unroll
    for (int d = 32; d > 0; d >>= 1) var += __shfl_xor(var, d);
    var *= (1.0f / 64.0f);
    out[(size_t)n * 64 + lane] = dv * rsqrtf(var + LN_EPS) * gamma[lane] + beta[lane];
}

// ---------------------------------------------------------------------------
extern "C" void kernel_launch(void* const* d_in, const int* in_sizes, int n_in,
                              void* d_out, int out_size, void* d_ws, size_t ws_size,
                              hipStream_t stream) {
    const float* X        = (const float*)d_in[0];
    const int*   ei       = (const int*)d_in[1];
    const float* W        = (const float*)d_in[2];
    const float* att_src  = (const float*)d_in[3];
    const float* att_dst  = (const float*)d_in[4];
    const float* bias     = (const float*)d_in[5];
    const float* ln_gamma = (const float*)d_in[6];
    const float* ln_beta  = (const float*)d_in[7];
    float* out = (float*)d_out;

    const int N = in_sizes[0] / 128;
    const int E = in_sizes[1] / 2;
    const int NB = (E + SORT_CHUNK - 1) / SORT_CHUNK;
    const int NBUCK = (N + 255) / 256;
    const int M = NBIN * NB;

    char* ws = (char*)d_ws;
    size_t off = 0;
    auto alloc = [&](size_t bytes) {
        size_t o = off;
        off += (bytes + 255) & ~(size_t)255;
        return o;
    };
    unsigned int* xp     = (unsigned int*)(ws + alloc((size_t)N * 64 * 4));
    float2* aS           = (float2*)(ws + alloc((size_t)N * 8));
    float2* aD           = (float2*)(ws + alloc((size_t)N * 8));
    float2* alphaSelf    = (float2*)(ws + alloc((size_t)N * 8));
    int* row_ptr         = (int*)(ws + alloc((size_t)(N + 1) * 4));
    uint2* csr           = (uint2*)(ws + alloc((size_t)E * 8));
    uint2* tmp           = (uint2*)(ws + alloc((size_t)E * 8));
    unsigned int* uW     = (unsigned int*)(ws + alloc((size_t)E * 4));
    int* blockCnt        = (int*)(ws + alloc((size_t)M * 4));
    int* blockSums       = (int*)(ws + alloc(256 * 4));
    unsigned short* Wb   = (unsigned short*)(ws + alloc(128 * 128 * 2));

    k_wconv<<<16, 256, 0, stream>>>(W, Wb);
    k_gemm<<<(N + 63) / 64, 256, 0, stream>>>(X, Wb, att_src, att_dst, xp, aS, aD, N);

    k_uw<<<(E + 255) / 256, 256, 0, stream>>>(ei, aS, aD, uW, E);
    k_sort_count<<<NB, 256, 0, stream>>>(ei, blockCnt, E, NB);
    const int nb = (M + 1023) / 1024;
    k_scan1<<<nb, 256, 0, stream>>>(blockCnt, blockSums, M);
    k_scan2<<<1, 256, 0, stream>>>(blockSums, nb);
    k_scan3<<<nb, 256, 0, stream>>>(blockCnt, blockSums, M);
    k_sort_scatter<<<NB, 256, 0, stream>>>(ei, uW, blockCnt, tmp, E, NB);
    k_bucket<<<NBUCK, 256, 0, stream>>>(tmp, blockCnt, aS, aD,
                                        csr, row_ptr, alphaSelf, E, NB, N);

    k_agg<<<(N + 3) / 4, 256, 0, stream>>>(xp, alphaSelf, row_ptr, csr,
                                           bias, ln_gamma, ln_beta, out, N);
}

// Round 7
// 277.953 us; speedup vs baseline: 1.3063x; 1.0668x over previous
//
#include <hip/hip_runtime.h>
#include <hip/hip_bf16.h>

#define NEG_SLOPE 0.2f
#define LN_EPS 1e-5f
#define SM_EPS 1e-16f

typedef __attribute__((ext_vector_type(8))) short bf16x8;
typedef __attribute__((ext_vector_type(4))) float f32x4;

__device__ inline unsigned short f2bf(float f) {
    unsigned u = __float_as_uint(f);
    return (unsigned short)((u + 0x7FFFu + ((u >> 16) & 1u)) >> 16);
}
__device__ inline float bf_lo(unsigned int v) { return __uint_as_float(v << 16); }
__device__ inline float bf_hi(unsigned int v) { return __uint_as_float(v & 0xffff0000u); }

// ---------------------------------------------------------------------------
// k_wconv: one-time W (f32 [128x128]) -> bf16 row-major Wb.
// ---------------------------------------------------------------------------
__global__ __launch_bounds__(256) void k_wconv(const float* __restrict__ W,
                                               unsigned short* __restrict__ Wb) {
    int i = blockIdx.x * 256 + threadIdx.x;
    float4 v = reinterpret_cast<const float4*>(W)[i];
    ushort4 b;
    b.x = f2bf(v.x); b.y = f2bf(v.y); b.z = f2bf(v.z); b.w = f2bf(v.w);
    reinterpret_cast<ushort4*>(Wb)[i] = b;
}

// ---------------------------------------------------------------------------
// K1: bf16-MFMA GEMM + attention dots + bf16 pack. (verified since r5)
// ---------------------------------------------------------------------------
__global__ __launch_bounds__(256) void k_gemm(const float* __restrict__ X,
                                              const unsigned short* __restrict__ Wb,
                                              const float* __restrict__ att_src,
                                              const float* __restrict__ att_dst,
                                              unsigned int* __restrict__ xp,
                                              float2* __restrict__ aS,
                                              float2* __restrict__ aD, int N) {
    __shared__ unsigned short Xs[64 * 136];
    const int t = threadIdx.x;
    const int b0 = blockIdx.x * 64;
    const int lane = t & 63;
    const int w = t >> 6;
    const int c15 = lane & 15;
    const int quad = lane >> 4;

#pragma unroll
    for (int i = 0; i < 8; ++i) {
        int f = i * 256 + t;
        int m = f >> 5;
        int q = f & 31;
        int gr = b0 + m;
        if (gr >= N) gr = N - 1;
        float4 v = reinterpret_cast<const float4*>(X)[(size_t)gr * 32 + q];
        ushort4 b;
        b.x = f2bf(v.x); b.y = f2bf(v.y); b.z = f2bf(v.z); b.w = f2bf(v.w);
        *reinterpret_cast<ushort4*>(&Xs[m * 136 + q * 4]) = b;
    }
    __syncthreads();

    f32x4 acc[8];
#pragma unroll
    for (int ct = 0; ct < 8; ++ct) acc[ct] = (f32x4){0.f, 0.f, 0.f, 0.f};

#pragma unroll
    for (int kc = 0; kc < 4; ++kc) {
        bf16x8 af = *reinterpret_cast<const bf16x8*>(
            &Xs[(w * 16 + c15) * 136 + kc * 32 + quad * 8]);
#pragma unroll
        for (int ct = 0; ct < 8; ++ct) {
            bf16x8 bfr = *reinterpret_cast<const bf16x8*>(
                &Wb[(ct * 16 + c15) * 128 + kc * 32 + quad * 8]);
            acc[ct] = __builtin_amdgcn_mfma_f32_16x16x32_bf16(af, bfr, acc[ct], 0, 0, 0);
        }
    }

    float attS[8], attD[8];
#pragma unroll
    for (int ct = 0; ct < 8; ++ct) {
        attS[ct] = att_src[ct * 16 + c15];
        attD[ct] = att_dst[ct * 16 + c15];
    }

#pragma unroll
    for (int r = 0; r < 4; ++r) {
        int row = b0 + w * 16 + quad * 4 + r;
        float s0 = 0.f, s1 = 0.f, d0 = 0.f, d1 = 0.f;
#pragma unroll
        for (int ct = 0; ct < 4; ++ct) {
            s0 += acc[ct][r] * attS[ct];
            d0 += acc[ct][r] * attD[ct];
            s1 += acc[ct + 4][r] * attS[ct + 4];
            d1 += acc[ct + 4][r] * attD[ct + 4];
        }
#pragma unroll
        for (int o = 1; o < 16; o <<= 1) {
            s0 += __shfl_xor(s0, o);
            s1 += __shfl_xor(s1, o);
            d0 += __shfl_xor(d0, o);
            d1 += __shfl_xor(d1, o);
        }
        if (row < N) {
#pragma unroll
            for (int ct = 0; ct < 4; ++ct) {
                unsigned int p = (unsigned int)f2bf(acc[ct][r]) |
                                 ((unsigned int)f2bf(acc[ct + 4][r]) << 16);
                xp[(size_t)row * 64 + ct * 16 + c15] = p;
            }
            if (c15 == 0) {
                aS[row] = make_float2(s0, s1);
                aD[row] = make_float2(d0, d1);
            }
        }
    }
}

// ---------------------------------------------------------------------------
// k_uw: one thread per edge, full grid (oversubscribed -> gather latency
// hidden). exp weights computed once, written coalesced.
// ---------------------------------------------------------------------------
__global__ __launch_bounds__(256) void k_uw(const int* __restrict__ ei,
                                            const float2* __restrict__ aS,
                                            const float2* __restrict__ aD,
                                            unsigned int* __restrict__ uW, int E) {
    int i = blockIdx.x * 256 + threadIdx.x;
    if (i >= E) return;
    int s = ei[i];
    int d = ei[E + i];
    float2 a = aS[s];
    float2 ad2 = aD[d];
    float f0 = a.x + ad2.x; f0 = fmaxf(f0, NEG_SLOPE * f0);
    float f1 = a.y + ad2.y; f1 = fmaxf(f1, NEG_SLOPE * f1);
    uW[i] = (unsigned int)f2bf(__expf(f0)) |
            ((unsigned int)f2bf(__expf(f1)) << 16);
}

// ---------------------------------------------------------------------------
// Atomic-free CSR build via 2-level counting sort on dst. CHUNK=4096.
// ---------------------------------------------------------------------------
#define SORT_CHUNK 4096
#define NBIN 512

__global__ __launch_bounds__(256) void k_sort_count(const int* __restrict__ ei,
                                                    int* __restrict__ blockCnt,
                                                    int E, int NB) {
    __shared__ int hist[NBIN];
    const int t = threadIdx.x;
    for (int i = t; i < NBIN; i += 256) hist[i] = 0;
    __syncthreads();
    const int base = blockIdx.x * SORT_CHUNK;
#pragma unroll
    for (int k = 0; k < 16; ++k) {
        int i = base + k * 256 + t;
        if (i < E) atomicAdd(&hist[ei[E + i] >> 8], 1);
    }
    __syncthreads();
    for (int i = t; i < NBIN; i += 256)
        blockCnt[i * NB + blockIdx.x] = hist[i];
}

__global__ __launch_bounds__(256) void k_scan1(const int* __restrict__ data,
                                               int* __restrict__ blockSums, int M) {
    __shared__ int lds[4];
    const int t = threadIdx.x;
    int base = blockIdx.x * 1024 + t * 4;
    int s = 0;
    for (int c = 0; c < 4; ++c) {
        int i = base + c;
        if (i < M) s += data[i];
    }
    int lane = t & 63, w = t >> 6;
    for (int o = 32; o > 0; o >>= 1) s += __shfl_down(s, o);
    if (lane == 0) lds[w] = s;
    __syncthreads();
    if (t == 0) blockSums[blockIdx.x] = lds[0] + lds[1] + lds[2] + lds[3];
}

__global__ void k_scan2(int* __restrict__ blockSums, int nb) {
    __shared__ int buf[256];
    const int t = threadIdx.x;
    int v = (t < nb) ? blockSums[t] : 0;
    buf[t] = v;
    __syncthreads();
    for (int o = 1; o < 256; o <<= 1) {
        int u = (t >= o) ? buf[t - o] : 0;
        __syncthreads();
        buf[t] += u;
        __syncthreads();
    }
    if (t < nb) blockSums[t] = buf[t] - v;
}

__global__ __launch_bounds__(256) void k_scan3(int* __restrict__ data,
                                               const int* __restrict__ blockSums, int M) {
    __shared__ int lds[4];
    const int t = threadIdx.x;
    int base = blockIdx.x * 1024 + t * 4;
    int c[4];
    int s = 0;
#pragma unroll
    for (int i = 0; i < 4; ++i) {
        int idx = base + i;
        c[i] = (idx < M) ? data[idx] : 0;
        s += c[i];
    }
    int lane = t & 63, w = t >> 6;
    int incl = s;
#pragma unroll
    for (int o = 1; o < 64; o <<= 1) {
        int u = __shfl_up(incl, o);
        if (lane >= o) incl += u;
    }
    if (lane == 63) lds[w] = incl;
    __syncthreads();
    if (t == 0) {
        int run = 0;
        for (int i = 0; i < 4; ++i) { int tmp = lds[i]; lds[i] = run; run += tmp; }
    }
    __syncthreads();
    int off = blockSums[blockIdx.x] + lds[w] + incl - s;
#pragma unroll
    for (int i = 0; i < 4; ++i) {
        int idx = base + i;
        if (idx < M) { data[idx] = off; off += c[i]; }
    }
}

__global__ __launch_bounds__(256) void k_sort_scatter(const int* __restrict__ ei,
                                                      const unsigned int* __restrict__ uW,
                                                      const int* __restrict__ scanned,
                                                      uint2* __restrict__ tmp,
                                                      int E, int NB) {
    __shared__ int off[NBIN];
    const int t = threadIdx.x;
    for (int i = t; i < NBIN; i += 256) off[i] = scanned[i * NB + blockIdx.x];
    __syncthreads();
    const int base = blockIdx.x * SORT_CHUNK;
#pragma unroll
    for (int k = 0; k < 16; ++k) {
        int i = base + k * 256 + t;
        if (i < E) {
            int s = ei[i];
            int d = ei[E + i];
            unsigned int u = uW[i];
            int p = atomicAdd(&off[d >> 8], 1);
            tmp[p] = make_uint2(((unsigned)(d & 255) << 24) | (unsigned)s, u);
        }
    }
}

// ---------------------------------------------------------------------------
// k_bucket: one block per 256-dst bucket.
// P1: denominators/counts from tmp (coalesced). Then row_ptr + per-dst meta
// {uSelf0, uSelf1, 0.5/D0, 0.5/D1}. P2: pure permutation copy (src,u) -> csr.
// Normalization deferred to k_agg (per-dst constant, applied after the loop).
// ---------------------------------------------------------------------------
__global__ __launch_bounds__(256) void k_bucket(const uint2* __restrict__ tmp,
                                                const int* __restrict__ scanned,
                                                const float2* __restrict__ aS,
                                                const float2* __restrict__ aD,
                                                uint2* __restrict__ csr,
                                                int* __restrict__ row_ptr,
                                                float4* __restrict__ metaN,
                                                int E, int NB, int N) {
    __shared__ int cnt[256];
    __shared__ int cur[256];
    __shared__ float den0[256], den1[256];
    __shared__ int lds[4];
    const int t = threadIdx.x;
    const int b = blockIdx.x;
    const int start = scanned[b * NB];
    const int end = (b + 1 < NBIN) ? scanned[(b + 1) * NB] : E;
    const int m = end - start;

    cnt[t] = 0; den0[t] = 0.f; den1[t] = 0.f;
    __syncthreads();

    for (int k = t; k < m; k += 256) {
        uint2 e = tmp[start + k];
        int li = e.x >> 24;
        atomicAdd(&cnt[li], 1);
        atomicAdd(&den0[li], bf_lo(e.y));
        atomicAdd(&den1[li], bf_hi(e.y));
    }
    __syncthreads();

    int v = cnt[t];
    int lane = t & 63, w = t >> 6;
    int incl = v;
#pragma unroll
    for (int o = 1; o < 64; o <<= 1) {
        int u = __shfl_up(incl, o);
        if (lane >= o) incl += u;
    }
    if (lane == 63) lds[w] = incl;
    __syncthreads();
    if (t == 0) {
        int run = 0;
        for (int i = 0; i < 4; ++i) { int tmpv = lds[i]; lds[i] = run; run += tmpv; }
    }
    __syncthreads();
    int excl = lds[w] + incl - v;
    cur[t] = start + excl;

    int d = b * 256 + t;
    if (d < N) {
        float2 a = aS[d];
        float2 ad2 = aD[d];
        float f0 = a.x + ad2.x; f0 = fmaxf(f0, NEG_SLOPE * f0);
        float f1 = a.y + ad2.y; f1 = fmaxf(f1, NEG_SLOPE * f1);
        float ws0 = __expf(f0), ws1 = __expf(f1);
        float D0 = den0[t] + ws0, D1 = den1[t] + ws1;
        metaN[d] = make_float4(ws0, ws1,
                               0.5f / (D0 + SM_EPS), 0.5f / (D1 + SM_EPS));
        row_ptr[d] = start + excl;
    }
    if (b == 0 && t == 0) row_ptr[N] = E;
    __syncthreads();

    for (int k = t; k < m; k += 256) {
        uint2 e = tmp[start + k];
        int li = e.x >> 24;
        int p = atomicAdd(&cur[li], 1);
        csr[p] = make_uint2(e.x & 0x00FFFFFFu, e.y);
    }
}

// ---------------------------------------------------------------------------
// K5: per-dst aggregation + bias + LayerNorm. Unroll-8, scalar-cache CSR
// loads (wave-uniform index via readfirstlane), invD applied after the loop.
// ---------------------------------------------------------------------------
__global__ __launch_bounds__(256) void k_agg(const unsigned int* __restrict__ xp,
                                             const float4* __restrict__ metaN,
                                             const int* __restrict__ row_ptr,
                                             const uint2* __restrict__ csr,
                                             const float* __restrict__ bias,
                                             const float* __restrict__ gamma,
                                             const float* __restrict__ beta,
                                             float* __restrict__ out, int N) {
    const int w = threadIdx.x >> 6, lane = threadIdx.x & 63;
    const int n = blockIdx.x * 4 + w;
    if (n >= N) return;

    float4 meta = metaN[n];   // uSelf0, uSelf1, 0.5/D0, 0.5/D1
    unsigned int vself = xp[(size_t)n * 64 + lane];
    float S0 = meta.x * bf_lo(vself);
    float S1 = meta.y * bf_hi(vself);

    const int jb = row_ptr[n], je = row_ptr[n + 1];
    int j = jb;
    for (; j + 7 < je; j += 8) {
        int ju = __builtin_amdgcn_readfirstlane(j);
        uint2 c[8];
#pragma unroll
        for (int q = 0; q < 8; ++q) c[q] = csr[ju + q];
        unsigned int v[8];
#pragma unroll
        for (int q = 0; q < 8; ++q) v[q] = xp[(size_t)c[q].x * 64 + lane];
#pragma unroll
        for (int q = 0; q < 8; ++q) {
            S0 += bf_lo(c[q].y) * bf_lo(v[q]);
            S1 += bf_hi(c[q].y) * bf_hi(v[q]);
        }
    }
    for (; j + 3 < je; j += 4) {
        int ju = __builtin_amdgcn_readfirstlane(j);
        uint2 c[4];
#pragma unroll
        for (int q = 0; q < 4; ++q) c[q] = csr[ju + q];
        unsigned int v[4];
#pragma unroll
        for (int q = 0; q < 4; ++q) v[q] = xp[(size_t)c[q].x * 64 + lane];
#pragma unroll
        for (int q = 0; q < 4; ++q) {
            S0 += bf_lo(c[q].y) * bf_lo(v[q]);
            S1 += bf_hi(c[q].y) * bf_hi(v[q]);
        }
    }
    for (; j < je; ++j) {
        uint2 c = csr[__builtin_amdgcn_readfirstlane(j)];
        unsigned int vv = xp[(size_t)c.x * 64 + lane];
        S0 += bf_lo(c.y) * bf_lo(vv);
        S1 += bf_hi(c.y) * bf_hi(vv);
    }

    float o = meta.z * S0 + meta.w * S1 + bias[lane];

    float mu = o;
#pragma unroll
    for (int d = 32; d > 0; d >>= 1) mu += __shfl_xor(mu, d);
    mu *= (1.0f / 64.0f);
    float dv = o - mu;
    float var = dv * dv;
#pragma unroll
    for (int d = 32; d > 0; d >>= 1) var += __shfl_xor(var, d);
    var *= (1.0f / 64.0f);
    out[(size_t)n * 64 + lane] = dv * rsqrtf(var + LN_EPS) * gamma[lane] + beta[lane];
}

// ---------------------------------------------------------------------------
extern "C" void kernel_launch(void* const* d_in, const int* in_sizes, int n_in,
                              void* d_out, int out_size, void* d_ws, size_t ws_size,
                              hipStream_t stream) {
    const float* X        = (const float*)d_in[0];
    const int*   ei       = (const int*)d_in[1];
    const float* W        = (const float*)d_in[2];
    const float* att_src  = (const float*)d_in[3];
    const float* att_dst  = (const float*)d_in[4];
    const float* bias     = (const float*)d_in[5];
    const float* ln_gamma = (const float*)d_in[6];
    const float* ln_beta  = (const float*)d_in[7];
    float* out = (float*)d_out;

    const int N = in_sizes[0] / 128;
    const int E = in_sizes[1] / 2;
    const int NB = (E + SORT_CHUNK - 1) / SORT_CHUNK;
    const int NBUCK = (N + 255) / 256;
    const int M = NBIN * NB;

    char* ws = (char*)d_ws;
    size_t off = 0;
    auto alloc = [&](size_t bytes) {
        size_t o = off;
        off += (bytes + 255) & ~(size_t)255;
        return o;
    };
    unsigned int* xp     = (unsigned int*)(ws + alloc((size_t)N * 64 * 4));
    float2* aS           = (float2*)(ws + alloc((size_t)N * 8));
    float2* aD           = (float2*)(ws + alloc((size_t)N * 8));
    float4* metaN        = (float4*)(ws + alloc((size_t)N * 16));
    int* row_ptr         = (int*)(ws + alloc((size_t)(N + 1) * 4));
    uint2* csr           = (uint2*)(ws + alloc((size_t)E * 8));
    uint2* tmp           = (uint2*)(ws + alloc((size_t)E * 8));
    unsigned int* uW     = (unsigned int*)(ws + alloc((size_t)E * 4));
    int* blockCnt        = (int*)(ws + alloc((size_t)M * 4));
    int* blockSums       = (int*)(ws + alloc(256 * 4));
    unsigned short* Wb   = (unsigned short*)(ws + alloc(128 * 128 * 2));

    k_wconv<<<16, 256, 0, stream>>>(W, Wb);
    k_gemm<<<(N + 63) / 64, 256, 0, stream>>>(X, Wb, att_src, att_dst, xp, aS, aD, N);

    k_uw<<<(E + 255) / 256, 256, 0, stream>>>(ei, aS, aD, uW, E);
    k_sort_count<<<NB, 256, 0, stream>>>(ei, blockCnt, E, NB);
    const int nb = (M + 1023) / 1024;
    k_scan1<<<nb, 256, 0, stream>>>(blockCnt, blockSums, M);
    k_scan2<<<1, 256, 0, stream>>>(blockSums, nb);
    k_scan3<<<nb, 256, 0, stream>>>(blockCnt, blockSums, M);
    k_sort_scatter<<<NB, 256, 0, stream>>>(ei, uW, blockCnt, tmp, E, NB);
    k_bucket<<<NBUCK, 256, 0, stream>>>(tmp, blockCnt, aS, aD,
                                        csr, row_ptr, metaN, E, NB, N);

    k_agg<<<(N + 3) / 4, 256, 0, stream>>>(xp, metaN, row_ptr, csr,
                                           bias, ln_gamma, ln_beta, out, N);
}

// Round 8
// 252.135 us; speedup vs baseline: 1.4400x; 1.1024x over previous
//
#include <hip/hip_runtime.h>
#include <hip/hip_bf16.h>

#define NEG_SLOPE 0.2f
#define LN_EPS 1e-5f
#define SM_EPS 1e-16f

typedef __attribute__((ext_vector_type(8))) short bf16x8;
typedef __attribute__((ext_vector_type(4))) float f32x4;

__device__ inline unsigned short f2bf(float f) {
    unsigned u = __float_as_uint(f);
    return (unsigned short)((u + 0x7FFFu + ((u >> 16) & 1u)) >> 16);
}
__device__ inline float bf_lo(unsigned int v) { return __uint_as_float(v << 16); }
__device__ inline float bf_hi(unsigned int v) { return __uint_as_float(v & 0xffff0000u); }

#define NBIN 512
#define SORT_CHUNK 4096

// ---------------------------------------------------------------------------
// K1: bf16-MFMA GEMM + attention dots + bf16 pack. W converted to bf16 in
// LDS per block (r2-r4 proven pattern; kills the separate k_wconv launch).
// LDS 52KB -> 3 blocks/CU.
// ---------------------------------------------------------------------------
__global__ __launch_bounds__(256) void k_gemm(const float* __restrict__ X,
                                              const float* __restrict__ W,
                                              const float* __restrict__ att_src,
                                              const float* __restrict__ att_dst,
                                              unsigned int* __restrict__ xp,
                                              float2* __restrict__ aS,
                                              float2* __restrict__ aD, int N) {
    __shared__ unsigned short Ws[128 * 136];
    __shared__ unsigned short Xs[64 * 136];
    const int t = threadIdx.x;
    const int b0 = blockIdx.x * 64;
    const int lane = t & 63;
    const int w = t >> 6;
    const int c15 = lane & 15;
    const int quad = lane >> 4;

#pragma unroll
    for (int i = 0; i < 16; ++i) {
        int f = i * 256 + t;
        int nr = f >> 5;
        int q = f & 31;
        float4 v = reinterpret_cast<const float4*>(W)[nr * 32 + q];
        ushort4 b;
        b.x = f2bf(v.x); b.y = f2bf(v.y); b.z = f2bf(v.z); b.w = f2bf(v.w);
        *reinterpret_cast<ushort4*>(&Ws[nr * 136 + q * 4]) = b;
    }
#pragma unroll
    for (int i = 0; i < 8; ++i) {
        int f = i * 256 + t;
        int m = f >> 5;
        int q = f & 31;
        int gr = b0 + m;
        if (gr >= N) gr = N - 1;
        float4 v = reinterpret_cast<const float4*>(X)[(size_t)gr * 32 + q];
        ushort4 b;
        b.x = f2bf(v.x); b.y = f2bf(v.y); b.z = f2bf(v.z); b.w = f2bf(v.w);
        *reinterpret_cast<ushort4*>(&Xs[m * 136 + q * 4]) = b;
    }
    __syncthreads();

    f32x4 acc[8];
#pragma unroll
    for (int ct = 0; ct < 8; ++ct) acc[ct] = (f32x4){0.f, 0.f, 0.f, 0.f};

#pragma unroll
    for (int kc = 0; kc < 4; ++kc) {
        bf16x8 af = *reinterpret_cast<const bf16x8*>(
            &Xs[(w * 16 + c15) * 136 + kc * 32 + quad * 8]);
#pragma unroll
        for (int ct = 0; ct < 8; ++ct) {
            bf16x8 bfr = *reinterpret_cast<const bf16x8*>(
                &Ws[(ct * 16 + c15) * 136 + kc * 32 + quad * 8]);
            acc[ct] = __builtin_amdgcn_mfma_f32_16x16x32_bf16(af, bfr, acc[ct], 0, 0, 0);
        }
    }

    float attS[8], attD[8];
#pragma unroll
    for (int ct = 0; ct < 8; ++ct) {
        attS[ct] = att_src[ct * 16 + c15];
        attD[ct] = att_dst[ct * 16 + c15];
    }

#pragma unroll
    for (int r = 0; r < 4; ++r) {
        int row = b0 + w * 16 + quad * 4 + r;
        float s0 = 0.f, s1 = 0.f, d0 = 0.f, d1 = 0.f;
#pragma unroll
        for (int ct = 0; ct < 4; ++ct) {
            s0 += acc[ct][r] * attS[ct];
            d0 += acc[ct][r] * attD[ct];
            s1 += acc[ct + 4][r] * attS[ct + 4];
            d1 += acc[ct + 4][r] * attD[ct + 4];
        }
#pragma unroll
        for (int o = 1; o < 16; o <<= 1) {
            s0 += __shfl_xor(s0, o);
            s1 += __shfl_xor(s1, o);
            d0 += __shfl_xor(d0, o);
            d1 += __shfl_xor(d1, o);
        }
        if (row < N) {
#pragma unroll
            for (int ct = 0; ct < 4; ++ct) {
                unsigned int p = (unsigned int)f2bf(acc[ct][r]) |
                                 ((unsigned int)f2bf(acc[ct + 4][r]) << 16);
                xp[(size_t)row * 64 + ct * 16 + c15] = p;
            }
            if (c15 == 0) {
                aS[row] = make_float2(s0, s1);
                aD[row] = make_float2(d0, d1);
            }
        }
    }
}

// ---------------------------------------------------------------------------
// k_uw: 8 edges/thread. exp weights computed once (coalesced write) + fused
// per-block LDS bin histogram flushed to global binTotal via atomics.
// ---------------------------------------------------------------------------
__global__ __launch_bounds__(256) void k_uw(const int* __restrict__ ei,
                                            const float2* __restrict__ aS,
                                            const float2* __restrict__ aD,
                                            unsigned int* __restrict__ uW,
                                            int* __restrict__ binTotal, int E) {
    __shared__ int hist[NBIN];
    const int t = threadIdx.x;
    for (int i = t; i < NBIN; i += 256) hist[i] = 0;
    __syncthreads();
    const int base = blockIdx.x * 2048;
#pragma unroll
    for (int k = 0; k < 8; ++k) {
        int i = base + k * 256 + t;
        if (i < E) {
            int s = ei[i];
            int d = ei[E + i];
            float2 a = aS[s];
            float2 ad2 = aD[d];
            float f0 = a.x + ad2.x; f0 = fmaxf(f0, NEG_SLOPE * f0);
            float f1 = a.y + ad2.y; f1 = fmaxf(f1, NEG_SLOPE * f1);
            uW[i] = (unsigned int)f2bf(__expf(f0)) |
                    ((unsigned int)f2bf(__expf(f1)) << 16);
            atomicAdd(&hist[d >> 8], 1);
        }
    }
    __syncthreads();
    for (int i = t; i < NBIN; i += 256)
        if (hist[i]) atomicAdd(&binTotal[i], hist[i]);
}

// ---------------------------------------------------------------------------
// k_binscan: single block, 512 threads. Exclusive scan of binTotal ->
// binStart[513] and binCursor[512].
// ---------------------------------------------------------------------------
__global__ __launch_bounds__(512) void k_binscan(const int* __restrict__ binTotal,
                                                 int* __restrict__ binStart,
                                                 int* __restrict__ binCursor, int E) {
    __shared__ int buf[NBIN];
    const int t = threadIdx.x;
    int v = binTotal[t];
    buf[t] = v;
    __syncthreads();
    for (int o = 1; o < NBIN; o <<= 1) {
        int u = (t >= o) ? buf[t - o] : 0;
        __syncthreads();
        buf[t] += u;
        __syncthreads();
    }
    int excl = buf[t] - v;
    binStart[t] = excl;
    binCursor[t] = excl;
    if (t == NBIN - 1) binStart[NBIN] = buf[t];   // == E
}

// ---------------------------------------------------------------------------
// k_scatter: 16 edges/thread held in registers. Pass 1: LDS chunk-histogram.
// Reserve contiguous per-(block,bin) ranges via ONE global atomicAdd per
// non-empty bin. Pass 2: scatter uint2 {(dst&255)<<24|src, u} from regs.
// ---------------------------------------------------------------------------
__global__ __launch_bounds__(256) void k_scatter(const int* __restrict__ ei,
                                                 const unsigned int* __restrict__ uW,
                                                 int* __restrict__ binCursor,
                                                 uint2* __restrict__ tmp, int E) {
    __shared__ int off[NBIN];
    const int t = threadIdx.x;
    const int base = blockIdx.x * SORT_CHUNK;

    int se[16], de[16];
    unsigned int ue[16];
#pragma unroll
    for (int k = 0; k < 16; ++k) {
        int i = base + k * 256 + t;
        if (i < E) {
            se[k] = ei[i];
            de[k] = ei[E + i];
            ue[k] = uW[i];
        } else {
            de[k] = -1;
        }
    }

    for (int i = t; i < NBIN; i += 256) off[i] = 0;
    __syncthreads();
#pragma unroll
    for (int k = 0; k < 16; ++k)
        if (de[k] >= 0) atomicAdd(&off[de[k] >> 8], 1);
    __syncthreads();
    for (int i = t; i < NBIN; i += 256) {
        int h = off[i];
        off[i] = h ? atomicAdd(&binCursor[i], h) : 0;
    }
    __syncthreads();
#pragma unroll
    for (int k = 0; k < 16; ++k) {
        if (de[k] >= 0) {
            int p = atomicAdd(&off[de[k] >> 8], 1);
            tmp[p] = make_uint2(((unsigned)(de[k] & 255) << 24) | (unsigned)se[k],
                                ue[k]);
        }
    }
}

// ---------------------------------------------------------------------------
// k_bucket: one block per 256-dst bucket. P1: cnt-only LDS histogram.
// Block scan -> row_ptr + cursors. meta = {uSelf0, uSelf1} (denominator is
// accumulated in k_agg now). P2: pure permutation copy (src,u) -> csr.
// ---------------------------------------------------------------------------
__global__ __launch_bounds__(256) void k_bucket(const uint2* __restrict__ tmp,
                                                const int* __restrict__ binStart,
                                                const float2* __restrict__ aS,
                                                const float2* __restrict__ aD,
                                                uint2* __restrict__ csr,
                                                int* __restrict__ row_ptr,
                                                float2* __restrict__ metaN,
                                                int E, int N) {
    __shared__ int cnt[256];
    __shared__ int cur[256];
    __shared__ int lds[4];
    const int t = threadIdx.x;
    const int b = blockIdx.x;
    const int start = binStart[b];
    const int end = binStart[b + 1];
    const int m = end - start;

    cnt[t] = 0;
    __syncthreads();
    for (int k = t; k < m; k += 256) {
        uint2 e = tmp[start + k];
        atomicAdd(&cnt[e.x >> 24], 1);
    }
    __syncthreads();

    int v = cnt[t];
    int lane = t & 63, w = t >> 6;
    int incl = v;
#pragma unroll
    for (int o = 1; o < 64; o <<= 1) {
        int u = __shfl_up(incl, o);
        if (lane >= o) incl += u;
    }
    if (lane == 63) lds[w] = incl;
    __syncthreads();
    if (t == 0) {
        int run = 0;
        for (int i = 0; i < 4; ++i) { int tv = lds[i]; lds[i] = run; run += tv; }
    }
    __syncthreads();
    int excl = lds[w] + incl - v;
    cur[t] = start + excl;

    int d = b * 256 + t;
    if (d < N) {
        float2 a = aS[d];
        float2 ad2 = aD[d];
        float f0 = a.x + ad2.x; f0 = fmaxf(f0, NEG_SLOPE * f0);
        float f1 = a.y + ad2.y; f1 = fmaxf(f1, NEG_SLOPE * f1);
        metaN[d] = make_float2(__expf(f0), __expf(f1));
        row_ptr[d] = start + excl;
    }
    if (b == 0 && t == 0) row_ptr[N] = E;
    __syncthreads();

    for (int k = t; k < m; k += 256) {
        uint2 e = tmp[start + k];
        int p = atomicAdd(&cur[e.x >> 24], 1);
        csr[p] = make_uint2(e.x & 0x00FFFFFFu, e.y);
    }
}

// ---------------------------------------------------------------------------
// K5: per-dst aggregation + bias + LayerNorm. Unroll-8, scalar-cache CSR
// loads; denominators accumulated in-loop; 0.5/(D+eps) applied at the end.
// ---------------------------------------------------------------------------
__global__ __launch_bounds__(256) void k_agg(const unsigned int* __restrict__ xp,
                                             const float2* __restrict__ metaN,
                                             const int* __restrict__ row_ptr,
                                             const uint2* __restrict__ csr,
                                             const float* __restrict__ bias,
                                             const float* __restrict__ gamma,
                                             const float* __restrict__ beta,
                                             float* __restrict__ out, int N) {
    const int w = threadIdx.x >> 6, lane = threadIdx.x & 63;
    const int n = blockIdx.x * 4 + w;
    if (n >= N) return;

    float2 meta = metaN[n];   // uSelf0, uSelf1
    unsigned int vself = xp[(size_t)n * 64 + lane];
    float S0 = meta.x * bf_lo(vself);
    float S1 = meta.y * bf_hi(vself);
    float D0 = meta.x, D1 = meta.y;

    const int jb = row_ptr[n], je = row_ptr[n + 1];
    int j = jb;
    for (; j + 7 < je; j += 8) {
        int ju = __builtin_amdgcn_readfirstlane(j);
        uint2 c[8];
#pragma unroll
        for (int q = 0; q < 8; ++q) c[q] = csr[ju + q];
        unsigned int v[8];
#pragma unroll
        for (int q = 0; q < 8; ++q) v[q] = xp[(size_t)c[q].x * 64 + lane];
#pragma unroll
        for (int q = 0; q < 8; ++q) {
            float u0 = bf_lo(c[q].y), u1 = bf_hi(c[q].y);
            S0 += u0 * bf_lo(v[q]);
            S1 += u1 * bf_hi(v[q]);
            D0 += u0; D1 += u1;
        }
    }
    for (; j + 3 < je; j += 4) {
        int ju = __builtin_amdgcn_readfirstlane(j);
        uint2 c[4];
#pragma unroll
        for (int q = 0; q < 4; ++q) c[q] = csr[ju + q];
        unsigned int v[4];
#pragma unroll
        for (int q = 0; q < 4; ++q) v[q] = xp[(size_t)c[q].x * 64 + lane];
#pragma unroll
        for (int q = 0; q < 4; ++q) {
            float u0 = bf_lo(c[q].y), u1 = bf_hi(c[q].y);
            S0 += u0 * bf_lo(v[q]);
            S1 += u1 * bf_hi(v[q]);
            D0 += u0; D1 += u1;
        }
    }
    for (; j < je; ++j) {
        uint2 c = csr[__builtin_amdgcn_readfirstlane(j)];
        unsigned int vv = xp[(size_t)c.x * 64 + lane];
        float u0 = bf_lo(c.y), u1 = bf_hi(c.y);
        S0 += u0 * bf_lo(vv);
        S1 += u1 * bf_hi(vv);
        D0 += u0; D1 += u1;
    }

    float inv0 = 0.5f / (D0 + SM_EPS);
    float inv1 = 0.5f / (D1 + SM_EPS);
    float o = inv0 * S0 + inv1 * S1 + bias[lane];

    float mu = o;
#pragma unroll
    for (int d = 32; d > 0; d >>= 1) mu += __shfl_xor(mu, d);
    mu *= (1.0f / 64.0f);
    float dv = o - mu;
    float var = dv * dv;
#pragma unroll
    for (int d = 32; d > 0; d >>= 1) var += __shfl_xor(var, d);
    var *= (1.0f / 64.0f);
    out[(size_t)n * 64 + lane] = dv * rsqrtf(var + LN_EPS) * gamma[lane] + beta[lane];
}

// ---------------------------------------------------------------------------
extern "C" void kernel_launch(void* const* d_in, const int* in_sizes, int n_in,
                              void* d_out, int out_size, void* d_ws, size_t ws_size,
                              hipStream_t stream) {
    const float* X        = (const float*)d_in[0];
    const int*   ei       = (const int*)d_in[1];
    const float* W        = (const float*)d_in[2];
    const float* att_src  = (const float*)d_in[3];
    const float* att_dst  = (const float*)d_in[4];
    const float* bias     = (const float*)d_in[5];
    const float* ln_gamma = (const float*)d_in[6];
    const float* ln_beta  = (const float*)d_in[7];
    float* out = (float*)d_out;

    const int N = in_sizes[0] / 128;
    const int E = in_sizes[1] / 2;
    const int NBUCK = (N + 255) / 256;

    char* ws = (char*)d_ws;
    size_t off = 0;
    auto alloc = [&](size_t bytes) {
        size_t o = off;
        off += (bytes + 255) & ~(size_t)255;
        return o;
    };
    unsigned int* xp     = (unsigned int*)(ws + alloc((size_t)N * 64 * 4));
    float2* aS           = (float2*)(ws + alloc((size_t)N * 8));
    float2* aD           = (float2*)(ws + alloc((size_t)N * 8));
    float2* metaN        = (float2*)(ws + alloc((size_t)N * 8));
    int* row_ptr         = (int*)(ws + alloc((size_t)(N + 1) * 4));
    uint2* csr           = (uint2*)(ws + alloc((size_t)E * 8));
    uint2* tmp           = (uint2*)(ws + alloc((size_t)E * 8));
    unsigned int* uW     = (unsigned int*)(ws + alloc((size_t)E * 4));
    int* binTotal        = (int*)(ws + alloc((NBIN + 1) * 4));
    int* binStart        = (int*)(ws + alloc((NBIN + 1) * 4));
    int* binCursor       = (int*)(ws + alloc(NBIN * 4));

    hipMemsetAsync(binTotal, 0, NBIN * 4, stream);

    k_gemm<<<(N + 63) / 64, 256, 0, stream>>>(X, W, att_src, att_dst, xp, aS, aD, N);
    k_uw<<<(E + 2047) / 2048, 256, 0, stream>>>(ei, aS, aD, uW, binTotal, E);
    k_binscan<<<1, 512, 0, stream>>>(binTotal, binStart, binCursor, E);
    k_scatter<<<(E + SORT_CHUNK - 1) / SORT_CHUNK, 256, 0, stream>>>(ei, uW, binCursor, tmp, E);
    k_bucket<<<NBUCK, 256, 0, stream>>>(tmp, binStart, aS, aD, csr, row_ptr,
                                        metaN, E, N);
    k_agg<<<(N + 3) / 4, 256, 0, stream>>>(xp, metaN, row_ptr, csr,
                                           bias, ln_gamma, ln_beta, out, N);
}